// Round 7
// baseline (813.710 us; speedup 1.0000x reference)
//
#include <hip/hip_runtime.h>
#include <hip/hip_bf16.h>
#include <math.h>

#define NN   4096
#define EE   131072
#define HH   4
#define DIN  128
#define DH   256
#define DCAT 1024   /* HH*DH */
#define ALPHA_LR 0.2f
#define MAXDEG 256  /* degree cap for LDS stash; fallback recompute beyond */

typedef __attribute__((ext_vector_type(8))) short  short8;
typedef __attribute__((ext_vector_type(4))) short  s16x4;
typedef __attribute__((ext_vector_type(4))) float  f32x4;

__device__ __forceinline__ unsigned short f2bf(float f) {
    union { float f; unsigned u; } v; v.f = f;
    unsigned r = v.u + 0x7fffu + ((v.u >> 16) & 1u);
    return (unsigned short)(r >> 16);
}
__device__ __forceinline__ float bf2f(unsigned short us) {
    union { unsigned u; float f; } v; v.u = ((unsigned)us) << 16;
    return v.f;
}

// ------------------------------------------------------------------
// cast fp32 -> bf16, 4 elems/thread
// ------------------------------------------------------------------
__global__ void cast_kernel(const float* __restrict__ in, unsigned short* __restrict__ out, int n4)
{
    int i = blockIdx.x * 256 + threadIdx.x;
    if (i < n4) {
        f32x4 v = *(const f32x4*)(in + (size_t)i * 4);
        s16x4 o;
        o[0] = (short)f2bf(v[0]); o[1] = (short)f2bf(v[1]);
        o[2] = (short)f2bf(v[2]); o[3] = (short)f2bf(v[3]);
        *(s16x4*)(out + (size_t)i * 4) = o;
    }
}

// ------------------------------------------------------------------
// transpose+cast: W[h][K][256] fp32 -> BT[h*256+o][K] bf16
// ------------------------------------------------------------------
__global__ void transpose_cast_kernel(const float* __restrict__ W, unsigned short* __restrict__ BT, int K)
{
    __shared__ float tile[32][33];
    int h = blockIdx.z;
    int k0 = blockIdx.x * 32, o0 = blockIdx.y * 32;
    int tx = threadIdx.x & 31, ty = threadIdx.x >> 5;
    const float* Ws = W + (size_t)h * K * 256;
#pragma unroll
    for (int i = 0; i < 32; i += 8)
        tile[ty + i][tx] = Ws[(size_t)(k0 + ty + i) * 256 + o0 + tx];
    __syncthreads();
#pragma unroll
    for (int i = 0; i < 32; i += 8)
        BT[(size_t)(h * 256 + o0 + ty + i) * K + k0 + tx] = f2bf(tile[tx][ty + i]);
}

// W1/W2 combined (z<4 -> W1, else W2), K = DCAT
__global__ void transpose_cast2_kernel(const float* __restrict__ W1, const float* __restrict__ W2,
                                       unsigned short* __restrict__ BT1, unsigned short* __restrict__ BT2)
{
    __shared__ float tile[32][33];
    int z = blockIdx.z;
    int h = z & 3;
    const float* W = (z < 4) ? W1 : W2;
    unsigned short* BT = (z < 4) ? BT1 : BT2;
    int k0 = blockIdx.x * 32, o0 = blockIdx.y * 32;
    int tx = threadIdx.x & 31, ty = threadIdx.x >> 5;
    const float* Ws = W + (size_t)h * DCAT * 256;
#pragma unroll
    for (int i = 0; i < 32; i += 8)
        tile[ty + i][tx] = Ws[(size_t)(k0 + ty + i) * 256 + o0 + tx];
    __syncthreads();
#pragma unroll
    for (int i = 0; i < 32; i += 8)
        BT[(size_t)(h * 256 + o0 + ty + i) * DCAT + k0 + tx] = f2bf(tile[tx][ty + i]);
}

// ------------------------------------------------------------------
// bf16 MFMA GEMM: C = act(A[M][K] @ BT[N][K]^T + bias), 128x128 tile.
// Optional fused epilogue (av != null, ldc must be DCAT):
//   es4[row][h] += sum_o a[h][o]   * C[row][h*256+o]
//   ed4[row][h] += sum_o a[h][256+o]*C[row][h*256+o]
//   csum[col]   += sum_rows C[row][col]
// ------------------------------------------------------------------
__global__ __launch_bounds__(256)
void mfma_gemm_kernel(const unsigned short* __restrict__ A,
                      const unsigned short* __restrict__ BT,
                      int K,
                      unsigned short* __restrict__ Cb,
                      int ldc,
                      const float* __restrict__ bias, int relu_act,
                      const float* __restrict__ av,
                      float* __restrict__ es4, float* __restrict__ ed4,
                      float* __restrict__ csum)
{
    __shared__ __align__(16) unsigned short sA[2][128 * 32];
    __shared__ __align__(16) unsigned short sB[2][128 * 32];

    const int tid = threadIdx.x;
    const int w = tid >> 6, l = tid & 63;
    const int wr = w >> 1, wc = w & 1;
    const int row0 = blockIdx.x * 128, col0 = blockIdx.y * 128;
    const int lrow = l >> 2;
    const int lce  = (l & 3) * 8;
    const int lr = l & 15, lg = l >> 4;

    f32x4 acc[4][4];
#pragma unroll
    for (int m = 0; m < 4; ++m)
#pragma unroll
        for (int n = 0; n < 4; ++n)
            acc[m][n] = (f32x4){0.f, 0.f, 0.f, 0.f};

#define STAGE(buf, k0)                                                          \
    {                                                                           \
        _Pragma("unroll")                                                       \
        for (int p = 0; p < 2; ++p) {                                           \
            int chunk = w * 2 + p;                                              \
            int r = chunk * 16 + lrow;                                          \
            const unsigned short* ga = A  + (size_t)(row0 + r) * K + (k0) + lce;\
            const unsigned short* gb = BT + (size_t)(col0 + r) * K + (k0) + lce;\
            __builtin_amdgcn_global_load_lds(                                   \
                (const __attribute__((address_space(1))) unsigned int*)ga,      \
                (__attribute__((address_space(3))) unsigned int*)(&sA[buf][chunk * 512]), \
                16, 0, 0);                                                      \
            __builtin_amdgcn_global_load_lds(                                   \
                (const __attribute__((address_space(1))) unsigned int*)gb,      \
                (__attribute__((address_space(3))) unsigned int*)(&sB[buf][chunk * 512]), \
                16, 0, 0);                                                      \
        }                                                                       \
    }

#define COMPUTE(buf)                                                            \
    {                                                                           \
        short8 af[4], bfr[4];                                                   \
        _Pragma("unroll")                                                       \
        for (int m = 0; m < 4; ++m) {                                           \
            int r = wr * 64 + m * 16 + lr;                                      \
            af[m] = *(const short8*)(&sA[buf][r * 32 + lg * 8]);                \
        }                                                                       \
        _Pragma("unroll")                                                       \
        for (int n = 0; n < 4; ++n) {                                           \
            int r = wc * 64 + n * 16 + lr;                                      \
            bfr[n] = *(const short8*)(&sB[buf][r * 32 + lg * 8]);               \
        }                                                                       \
        _Pragma("unroll")                                                       \
        for (int m = 0; m < 4; ++m)                                             \
            _Pragma("unroll")                                                   \
            for (int n = 0; n < 4; ++n)                                         \
                acc[m][n] = __builtin_amdgcn_mfma_f32_16x16x32_bf16(            \
                    af[m], bfr[n], acc[m][n], 0, 0, 0);                         \
    }

    STAGE(0, 0);
    __syncthreads();
    int nt = K >> 5, cur = 0;
    for (int t = 0; t < nt - 1; ++t) {
        STAGE(cur ^ 1, (t + 1) * 32);
        COMPUTE(cur);
        __syncthreads();
        cur ^= 1;
    }
    COMPUTE(cur);
#undef STAGE
#undef COMPUTE

    // C-write
#pragma unroll
    for (int m = 0; m < 4; ++m) {
        int rbase = row0 + wr * 64 + m * 16 + lg * 4;
#pragma unroll
        for (int n = 0; n < 4; ++n) {
            int c = col0 + wc * 64 + n * 16 + lr;
            float bv = bias ? bias[c] : 0.f;
#pragma unroll
            for (int r = 0; r < 4; ++r) {
                float v = acc[m][n][r] + bv;
                if (relu_act) v = fmaxf(v, 0.f);
                Cb[(size_t)(rbase + r) * ldc + c] = f2bf(v);
            }
        }
    }

    // fused attvec + colsum epilogue
    if (av) {
        const int h = (col0 + wc * 64) >> 8;   // head uniform per wave quadrant
        float aes[4], aed[4];
#pragma unroll
        for (int n = 0; n < 4; ++n) {
            int cc = (col0 + wc * 64 + n * 16 + lr) & 255;
            aes[n] = av[h * 2 * DH + cc];
            aed[n] = av[h * 2 * DH + DH + cc];
        }
#pragma unroll
        for (int m = 0; m < 4; ++m) {
#pragma unroll
            for (int r = 0; r < 4; ++r) {
                float se = 0.f, sd = 0.f;
#pragma unroll
                for (int n = 0; n < 4; ++n) {
                    se = fmaf(aes[n], acc[m][n][r], se);
                    sd = fmaf(aed[n], acc[m][n][r], sd);
                }
                se += __shfl_xor(se, 1);  sd += __shfl_xor(sd, 1);
                se += __shfl_xor(se, 2);  sd += __shfl_xor(sd, 2);
                se += __shfl_xor(se, 4);  sd += __shfl_xor(sd, 4);
                se += __shfl_xor(se, 8);  sd += __shfl_xor(sd, 8);
                if (lr == 0) {
                    int row = row0 + wr * 64 + m * 16 + lg * 4 + r;
                    atomicAdd(&es4[row * 4 + h], se);
                    atomicAdd(&ed4[row * 4 + h], sd);
                }
            }
        }
#pragma unroll
        for (int n = 0; n < 4; ++n) {
            float s = 0.f;
#pragma unroll
            for (int m = 0; m < 4; ++m)
#pragma unroll
                for (int r = 0; r < 4; ++r)
                    s += acc[m][n][r];
            s += __shfl_xor(s, 16);
            s += __shfl_xor(s, 32);
            if (lg == 0) atomicAdd(&csum[col0 + wc * 64 + n * 16 + lr], s);
        }
    }
}

// ------------------------------------------------------------------
// CSR build
// ------------------------------------------------------------------
__global__ void count_kernel(const int* __restrict__ src, int* __restrict__ counts)
{
    int e = blockIdx.x * 256 + threadIdx.x;
    atomicAdd(&counts[src[e]], 1);
}

__global__ void scan_kernel(const int* __restrict__ counts, int* __restrict__ rowptr,
                            int* __restrict__ cursor)
{
    __shared__ int lsum[1024];
    int t = threadIdx.x;
    int base = t * 4;
    int c0 = counts[base], c1 = counts[base + 1], c2 = counts[base + 2], c3 = counts[base + 3];
    int s = c0 + c1 + c2 + c3;
    lsum[t] = s;
    __syncthreads();
    for (int off = 1; off < 1024; off <<= 1) {
        int v = (t >= off) ? lsum[t - off] : 0;
        __syncthreads();
        lsum[t] += v;
        __syncthreads();
    }
    int excl = lsum[t] - s;
    rowptr[base] = excl;          cursor[base] = excl;
    rowptr[base + 1] = excl + c0; cursor[base + 1] = excl + c0;
    rowptr[base + 2] = excl + c0 + c1; cursor[base + 2] = excl + c0 + c1;
    rowptr[base + 3] = excl + c0 + c1 + c2; cursor[base + 3] = excl + c0 + c1 + c2;
    if (t == 1023) rowptr[NN] = lsum[1023];
}

__global__ void fill_kernel(const int* __restrict__ src, const int* __restrict__ dst,
                            int* __restrict__ cursor, int* __restrict__ cdst)
{
    int e = blockIdx.x * 256 + threadIdx.x;
    int s = src[e];
    int pos = atomicAdd(&cursor[s], 1);
    cdst[pos] = dst[e];
}

// ------------------------------------------------------------------
// Fused edge-weights + denominator + aggregation + importance.
// One block per (node, head): the per-head Wh slice is 2 MB -> fits
// per-XCD L2. blockIdx decoded so each XCD handles one head only
// (perf heuristic via dispatch round-robin; correctness-independent).
// ------------------------------------------------------------------
__global__ __launch_bounds__(256)
void agg_kernel(const unsigned short* __restrict__ Whb,
                const float* __restrict__ es4, const float* __restrict__ ed4,  // [n][4]
                const float* __restrict__ csum,
                const int* __restrict__ rowptr, const int* __restrict__ cdst,
                float* __restrict__ imp, float* __restrict__ Ctot,
                unsigned short* __restrict__ hb_out)
{
    __shared__ float wlds[MAXDEG];   // 1 KB
    __shared__ int   dlds[MAXDEG];   // 1 KB
    __shared__ float red[4 * DH];    // 4 KB
    __shared__ float swred[4];
    const int b = blockIdx.x;
    const int xcd = b & 7;
    const int h = xcd >> 1;
    const int n = (b >> 3) + (xcd & 1) * (NN / 2);
    const int tid = threadIdx.x;
    const int w = tid >> 6, lane = tid & 63;
    const int beg = rowptr[n], end = rowptr[n + 1];
    const int deg = end - beg;
    const float esh = es4[n * 4 + h];

    // ---- Phase A: per-edge weights for this head ----
    float sw = 0.f;
    for (int i = tid; i < deg; i += 256) {
        int d = cdst[beg + i];
        float v = esh + ed4[d * 4 + h];
        v = v > 0.f ? v : ALPHA_LR * v;
        float wv = expm1f(v);
        sw += wv;
        if (i < MAXDEG) { wlds[i] = wv; dlds[i] = d; }
    }
#pragma unroll
    for (int off = 32; off; off >>= 1) sw += __shfl_down(sw, off);
    if (lane == 0) swred[w] = sw;
    __syncthreads();

    const float invd = 1.f / ((float)NN + swred[0] + swred[1] + swred[2] + swred[3]);
    if (tid == 0) atomicAdd(Ctot, invd);

    // importance scatter (per-head contribution)
    for (int i = tid; i < deg; i += 256) {
        float wv; int d;
        if (i < MAXDEG) { wv = wlds[i]; d = dlds[i]; }
        else {
            d = cdst[beg + i];
            float v = esh + ed4[d * 4 + h];
            v = v > 0.f ? v : ALPHA_LR * v;
            wv = expm1f(v);
        }
        atomicAdd(&imp[d], wv * invd);
    }

    // ---- Phase B: weighted gather over this head's 512B row chunks ----
    float acc[4] = {};
    const unsigned short* basep = Whb + h * DH + lane * 4;

#define GATHER_EDGE(i)                                                          \
    {                                                                           \
        float wv; int d;                                                        \
        if ((i) < MAXDEG) { wv = wlds[(i)]; d = dlds[(i)]; }                    \
        else {                                                                  \
            d = cdst[beg + (i)];                                                \
            float v = esh + ed4[d * 4 + h];                                     \
            v = v > 0.f ? v : ALPHA_LR * v;                                     \
            wv = expm1f(v);                                                     \
        }                                                                       \
        s16x4 vv = *(const s16x4*)(basep + (size_t)d * DCAT);                   \
        acc[0] = fmaf(wv, bf2f((unsigned short)vv[0]), acc[0]);                 \
        acc[1] = fmaf(wv, bf2f((unsigned short)vv[1]), acc[1]);                 \
        acc[2] = fmaf(wv, bf2f((unsigned short)vv[2]), acc[2]);                 \
        acc[3] = fmaf(wv, bf2f((unsigned short)vv[3]), acc[3]);                 \
    }

    for (int i = w * 2; i < deg; i += 8) {
        GATHER_EDGE(i);
        if (i + 1 < deg) GATHER_EDGE(i + 1);
    }
#undef GATHER_EDGE

    *(f32x4*)(&red[w * DH + lane * 4]) = (f32x4){acc[0], acc[1], acc[2], acc[3]};
    __syncthreads();

    // finish: thread t owns output o = t of this head
    const int t = tid;
    float s = red[t] + red[DH + t] + red[2 * DH + t] + red[3 * DH + t];
    float v = (csum[h * DH + t] + s) * invd;
    v = v > 0.f ? v : expm1f(v);
    hb_out[(size_t)n * DCAT + h * DH + t] = f2bf(v);
}

// ------------------------------------------------------------------
// Pooling + classifier (bf16 h3)
// ------------------------------------------------------------------
__global__ void pool_score_kernel(const unsigned short* __restrict__ h3, const float* __restrict__ pw,
                                  const float* __restrict__ pb, float* __restrict__ ps)
{
    int wave = threadIdx.x >> 6, lane = threadIdx.x & 63;
    int n = blockIdx.x * 4 + wave;
    const unsigned short* row = h3 + (size_t)n * DCAT;
    float s = 0.f;
#pragma unroll
    for (int i = 0; i < 4; ++i) {
        int o = (i * 64 + lane) * 4;
        s16x4 v = *(const s16x4*)(row + o);
        f32x4 a = *(const f32x4*)(pw + o);
#pragma unroll
        for (int j = 0; j < 4; ++j) s = fmaf(a[j], bf2f((unsigned short)v[j]), s);
    }
#pragma unroll
    for (int off = 32; off; off >>= 1) s += __shfl_down(s, off);
    if (lane == 0) ps[n] = s + pb[0];
}

__global__ void softmax_n_kernel(const float* __restrict__ s, float* __restrict__ aw)
{
    __shared__ float red[16];
    __shared__ float MM, SS;
    int t = threadIdx.x;
    float m = -1e30f;
    for (int i = t; i < NN; i += 1024) m = fmaxf(m, s[i]);
#pragma unroll
    for (int off = 32; off; off >>= 1) m = fmaxf(m, __shfl_down(m, off));
    if ((t & 63) == 0) red[t >> 6] = m;
    __syncthreads();
    if (t == 0) {
        float v = red[0];
        for (int i = 1; i < 16; ++i) v = fmaxf(v, red[i]);
        MM = v;
    }
    __syncthreads();
    float sum = 0.f;
    for (int i = t; i < NN; i += 1024) sum += expf(s[i] - MM);
#pragma unroll
    for (int off = 32; off; off >>= 1) sum += __shfl_down(sum, off);
    __syncthreads();
    if ((t & 63) == 0) red[t >> 6] = sum;
    __syncthreads();
    if (t == 0) {
        float v = 0.f;
        for (int i = 0; i < 16; ++i) v += red[i];
        SS = v;
    }
    __syncthreads();
    for (int i = t; i < NN; i += 1024) aw[i] = expf(s[i] - MM) / SS;
}

__global__ void emb_kernel(const unsigned short* __restrict__ h3, const float* __restrict__ aw,
                           float* __restrict__ emb)
{
    int o = blockIdx.x * 256 + threadIdx.x;
    int n0 = blockIdx.y * 256;
    float s = 0.f;
    for (int n = n0; n < n0 + 256; ++n)
        s = fmaf(aw[n], bf2f(h3[(size_t)n * DCAT + o]), s);
    atomicAdd(&emb[o], s);
}

// split-K matvec: zbuf[t] += sum_{j in block-chunk} emb[j]*c1w[j][t]
__global__ void c1_kernel(const float* __restrict__ emb, const float* __restrict__ c1w,
                          float* __restrict__ zbuf)
{
    int t = threadIdx.x;
    int r0 = blockIdx.x * 32;
    float s = 0.f;
#pragma unroll
    for (int j = 0; j < 32; ++j)
        s = fmaf(emb[r0 + j], c1w[(size_t)(r0 + j) * DH + t], s);
    atomicAdd(&zbuf[t], s);
}

__global__ void c2_kernel(const float* __restrict__ zbuf, const float* __restrict__ c1b,
                          const float* __restrict__ c2w, const float* __restrict__ c2b,
                          float* __restrict__ out)
{
    __shared__ float z[DH];
    __shared__ float lgs[8];
    int t = threadIdx.x;
    z[t] = fmaxf(zbuf[t] + c1b[t], 0.f);
    __syncthreads();
    int g = t >> 5, k = t & 31;
    if (g < 7) {
        float s = 0.f;
#pragma unroll
        for (int j = 0; j < 8; ++j)
            s = fmaf(z[k + 32 * j], c2w[(k + 32 * j) * 7 + g], s);
#pragma unroll
        for (int off = 16; off; off >>= 1) s += __shfl_down(s, off, 32);
        if (k == 0) lgs[g] = s + c2b[g];
    }
    __syncthreads();
    if (t == 0) {
        float m = lgs[0];
        for (int i = 1; i < 7; ++i) m = fmaxf(m, lgs[i]);
        float sm = 0.f, ex[7];
        for (int i = 0; i < 7; ++i) { ex[i] = expf(lgs[i] - m); sm += ex[i]; }
        for (int i = 0; i < 7; ++i) out[i] = ex[i] / sm;
    }
}

__global__ void natt_kernel(const float* __restrict__ imp, const float* __restrict__ Ctot,
                            float* __restrict__ out)
{
    int m = blockIdx.x * 256 + threadIdx.x;
    out[7 + m] = (imp[m] + Ctot[0]) * (1.0f / 12.0f);
}

// ------------------------------------------------------------------
extern "C" void kernel_launch(void* const* d_in, const int* in_sizes, int n_in,
                              void* d_out, int out_size, void* d_ws, size_t ws_size,
                              hipStream_t stream)
{
    const float* x   = (const float*)d_in[0];
    const int*   ei  = (const int*)d_in[1];
    const float* Wp  = (const float*)d_in[2];
    const float* bp  = (const float*)d_in[3];
    const float* W[3]  = {(const float*)d_in[4], (const float*)d_in[6], (const float*)d_in[8]};
    const float* av[3] = {(const float*)d_in[5], (const float*)d_in[7], (const float*)d_in[9]};
    const float* pw  = (const float*)d_in[10];
    const float* pb  = (const float*)d_in[11];
    const float* c1w = (const float*)d_in[12];
    const float* c1b = (const float*)d_in[13];
    const float* c2w = (const float*)d_in[14];
    const float* c2b = (const float*)d_in[15];
    float* out = (float*)d_out;
    (void)in_sizes; (void)n_in; (void)out_size; (void)ws_size;

    char* base = (char*)d_ws;
    size_t off = 0;
    auto alloc = [&](size_t bytes) -> void* {
        void* p = base + off;
        off = (off + bytes + 255) & ~(size_t)255;
        return p;
    };
    // ---- zero region (single memset) ----
    size_t zero_begin = off;
    float* es4_3 = (float*)alloc((size_t)3 * NN * 16);   // [layer][n][4]
    float* ed4_3 = (float*)alloc((size_t)3 * NN * 16);
    float* csum3 = (float*)alloc((size_t)3 * DCAT * 4);
    float* imp   = (float*)alloc(NN * 4);
    float* Ctot  = (float*)alloc(256);
    int*   counts = (int*)alloc(NN * 4);
    float* emb   = (float*)alloc(DCAT * 4);
    float* zbuf  = (float*)alloc(DH * 4);
    size_t zero_bytes = off - zero_begin;
    // ---- rest ----
    unsigned short* xb   = (unsigned short*)alloc((size_t)NN * DIN * 2);
    unsigned short* BTp  = (unsigned short*)alloc((size_t)DH * DIN * 2);
    unsigned short* BT0  = (unsigned short*)alloc((size_t)DCAT * DH * 2);
    unsigned short* BT1  = (unsigned short*)alloc((size_t)DCAT * DCAT * 2);
    unsigned short* BT2  = (unsigned short*)alloc((size_t)DCAT * DCAT * 2);
    unsigned short* Whb  = (unsigned short*)alloc((size_t)NN * DCAT * 2);
    unsigned short* hb0  = (unsigned short*)alloc((size_t)NN * DCAT * 2);
    unsigned short* hb1  = (unsigned short*)alloc((size_t)NN * DCAT * 2);
    int*   rowptr = (int*)alloc((NN + 1) * 4);
    int*   cursor = (int*)alloc(NN * 4);
    int*   cdst   = (int*)alloc((size_t)EE * 4);
    float* ps    = (float*)alloc(NN * 4);
    float* paw   = (float*)alloc(NN * 4);

    const int* srcp = ei;
    const int* dstp = ei + EE;

    hipMemsetAsync(base + zero_begin, 0, zero_bytes, stream);

    // CSR build
    count_kernel<<<EE / 256, 256, 0, stream>>>(srcp, counts);
    scan_kernel<<<1, 1024, 0, stream>>>(counts, rowptr, cursor);
    fill_kernel<<<EE / 256, 256, 0, stream>>>(srcp, dstp, cursor, cdst);

    // casts / repacks
    cast_kernel<<<(NN * DIN / 4 + 255) / 256, 256, 0, stream>>>(x, xb, NN * DIN / 4);
    transpose_cast_kernel<<<dim3(DIN / 32, 8, 1), 256, 0, stream>>>(Wp, BTp, DIN);
    transpose_cast_kernel<<<dim3(DH / 32, 8, HH), 256, 0, stream>>>(W[0], BT0, DH);
    transpose_cast2_kernel<<<dim3(DCAT / 32, 8, 8), 256, 0, stream>>>(W[1], W[2], BT1, BT2);

    // projection: hb0[N][256] = relu(x @ Wp + bp)
    mfma_gemm_kernel<<<dim3(NN / 128, DH / 128), 256, 0, stream>>>(
        xb, BTp, DIN, hb0, DH, bp, 1, nullptr, nullptr, nullptr, nullptr);

    unsigned short* cur = hb0;
    unsigned short* nxt = hb1;
    const unsigned short* BTl[3] = {BT0, BT1, BT2};
    for (int layer = 0; layer < 3; ++layer) {
        int K = (layer == 0) ? DH : DCAT;
        float* es = es4_3 + (size_t)layer * NN * 4;
        float* ed = ed4_3 + (size_t)layer * NN * 4;
        float* csum = csum3 + (size_t)layer * DCAT;
        mfma_gemm_kernel<<<dim3(NN / 128, DCAT / 128), 256, 0, stream>>>(
            cur, BTl[layer], K, Whb, DCAT, nullptr, 0, av[layer], es, ed, csum);
        agg_kernel<<<NN * HH, 256, 0, stream>>>(Whb, es, ed, csum, rowptr, cdst,
                                                imp, Ctot, nxt);
        unsigned short* t = cur; cur = nxt; nxt = t;
    }

    // pooling + classifier on bf16 h3 (cur)
    pool_score_kernel<<<NN / 4, 256, 0, stream>>>(cur, pw, pb, ps);
    softmax_n_kernel<<<1, 1024, 0, stream>>>(ps, paw);
    emb_kernel<<<dim3(DCAT / 256, NN / 256), 256, 0, stream>>>(cur, paw, emb);
    c1_kernel<<<32, 256, 0, stream>>>(emb, c1w, zbuf);
    c2_kernel<<<1, 256, 0, stream>>>(zbuf, c1b, c2w, c2b, out);
    natt_kernel<<<NN / 256, 256, 0, stream>>>(imp, Ctot, out);
}

// Round 8
// 382.715 us; speedup vs baseline: 2.1262x; 2.1262x over previous
//
#include <hip/hip_runtime.h>
#include <hip/hip_bf16.h>
#include <math.h>

#define NN   4096
#define EE   131072
#define HH   4
#define DIN  128
#define DH   256
#define DCAT 1024   /* HH*DH */
#define ALPHA_LR 0.2f
#define MAXDEG 256  /* degree cap for LDS stash; fallback recompute beyond */

typedef __attribute__((ext_vector_type(8))) short  short8;
typedef __attribute__((ext_vector_type(4))) short  s16x4;
typedef __attribute__((ext_vector_type(4))) float  f32x4;

__device__ __forceinline__ unsigned short f2bf(float f) {
    union { float f; unsigned u; } v; v.f = f;
    unsigned r = v.u + 0x7fffu + ((v.u >> 16) & 1u);
    return (unsigned short)(r >> 16);
}
__device__ __forceinline__ float bf2f(unsigned short us) {
    union { unsigned u; float f; } v; v.u = ((unsigned)us) << 16;
    return v.f;
}

// ------------------------------------------------------------------
// cast fp32 -> bf16, 4 elems/thread
// ------------------------------------------------------------------
__global__ void cast_kernel(const float* __restrict__ in, unsigned short* __restrict__ out, int n4)
{
    int i = blockIdx.x * 256 + threadIdx.x;
    if (i < n4) {
        f32x4 v = *(const f32x4*)(in + (size_t)i * 4);
        s16x4 o;
        o[0] = (short)f2bf(v[0]); o[1] = (short)f2bf(v[1]);
        o[2] = (short)f2bf(v[2]); o[3] = (short)f2bf(v[3]);
        *(s16x4*)(out + (size_t)i * 4) = o;
    }
}

// ------------------------------------------------------------------
// transpose+cast: W[h][K][256] fp32 -> BT[h*256+o][K] bf16
// ------------------------------------------------------------------
__global__ void transpose_cast_kernel(const float* __restrict__ W, unsigned short* __restrict__ BT, int K)
{
    __shared__ float tile[32][33];
    int h = blockIdx.z;
    int k0 = blockIdx.x * 32, o0 = blockIdx.y * 32;
    int tx = threadIdx.x & 31, ty = threadIdx.x >> 5;
    const float* Ws = W + (size_t)h * K * 256;
#pragma unroll
    for (int i = 0; i < 32; i += 8)
        tile[ty + i][tx] = Ws[(size_t)(k0 + ty + i) * 256 + o0 + tx];
    __syncthreads();
#pragma unroll
    for (int i = 0; i < 32; i += 8)
        BT[(size_t)(h * 256 + o0 + ty + i) * K + k0 + tx] = f2bf(tile[tx][ty + i]);
}

// W1/W2 combined (z<4 -> W1, else W2), K = DCAT
__global__ void transpose_cast2_kernel(const float* __restrict__ W1, const float* __restrict__ W2,
                                       unsigned short* __restrict__ BT1, unsigned short* __restrict__ BT2)
{
    __shared__ float tile[32][33];
    int z = blockIdx.z;
    int h = z & 3;
    const float* W = (z < 4) ? W1 : W2;
    unsigned short* BT = (z < 4) ? BT1 : BT2;
    int k0 = blockIdx.x * 32, o0 = blockIdx.y * 32;
    int tx = threadIdx.x & 31, ty = threadIdx.x >> 5;
    const float* Ws = W + (size_t)h * DCAT * 256;
#pragma unroll
    for (int i = 0; i < 32; i += 8)
        tile[ty + i][tx] = Ws[(size_t)(k0 + ty + i) * 256 + o0 + tx];
    __syncthreads();
#pragma unroll
    for (int i = 0; i < 32; i += 8)
        BT[(size_t)(h * 256 + o0 + ty + i) * DCAT + k0 + tx] = f2bf(tile[tx][ty + i]);
}

// ------------------------------------------------------------------
// bf16 MFMA GEMM: C = act(A[M][K] @ BT[N][K]^T + bias), 128x128 tile.
// Optional fused epilogue (av != null, ldc must be DCAT):
//   es4[row][h] += sum_o a[h][o]   * C[row][h*256+o]
//   ed4[row][h] += sum_o a[h][256+o]*C[row][h*256+o]
//   csum[col]   += sum_rows C[row][col]
// ------------------------------------------------------------------
__global__ __launch_bounds__(256)
void mfma_gemm_kernel(const unsigned short* __restrict__ A,
                      const unsigned short* __restrict__ BT,
                      int K,
                      unsigned short* __restrict__ Cb,
                      int ldc,
                      const float* __restrict__ bias, int relu_act,
                      const float* __restrict__ av,
                      float* __restrict__ es4, float* __restrict__ ed4,
                      float* __restrict__ csum)
{
    __shared__ __align__(16) unsigned short sA[2][128 * 32];
    __shared__ __align__(16) unsigned short sB[2][128 * 32];

    const int tid = threadIdx.x;
    const int w = tid >> 6, l = tid & 63;
    const int wr = w >> 1, wc = w & 1;
    const int row0 = blockIdx.x * 128, col0 = blockIdx.y * 128;
    const int lrow = l >> 2;
    const int lce  = (l & 3) * 8;
    const int lr = l & 15, lg = l >> 4;

    f32x4 acc[4][4];
#pragma unroll
    for (int m = 0; m < 4; ++m)
#pragma unroll
        for (int n = 0; n < 4; ++n)
            acc[m][n] = (f32x4){0.f, 0.f, 0.f, 0.f};

#define STAGE(buf, k0)                                                          \
    {                                                                           \
        _Pragma("unroll")                                                       \
        for (int p = 0; p < 2; ++p) {                                           \
            int chunk = w * 2 + p;                                              \
            int r = chunk * 16 + lrow;                                          \
            const unsigned short* ga = A  + (size_t)(row0 + r) * K + (k0) + lce;\
            const unsigned short* gb = BT + (size_t)(col0 + r) * K + (k0) + lce;\
            __builtin_amdgcn_global_load_lds(                                   \
                (const __attribute__((address_space(1))) unsigned int*)ga,      \
                (__attribute__((address_space(3))) unsigned int*)(&sA[buf][chunk * 512]), \
                16, 0, 0);                                                      \
            __builtin_amdgcn_global_load_lds(                                   \
                (const __attribute__((address_space(1))) unsigned int*)gb,      \
                (__attribute__((address_space(3))) unsigned int*)(&sB[buf][chunk * 512]), \
                16, 0, 0);                                                      \
        }                                                                       \
    }

#define COMPUTE(buf)                                                            \
    {                                                                           \
        short8 af[4], bfr[4];                                                   \
        _Pragma("unroll")                                                       \
        for (int m = 0; m < 4; ++m) {                                           \
            int r = wr * 64 + m * 16 + lr;                                      \
            af[m] = *(const short8*)(&sA[buf][r * 32 + lg * 8]);                \
        }                                                                       \
        _Pragma("unroll")                                                       \
        for (int n = 0; n < 4; ++n) {                                           \
            int r = wc * 64 + n * 16 + lr;                                      \
            bfr[n] = *(const short8*)(&sB[buf][r * 32 + lg * 8]);               \
        }                                                                       \
        _Pragma("unroll")                                                       \
        for (int m = 0; m < 4; ++m)                                             \
            _Pragma("unroll")                                                   \
            for (int n = 0; n < 4; ++n)                                         \
                acc[m][n] = __builtin_amdgcn_mfma_f32_16x16x32_bf16(            \
                    af[m], bfr[n], acc[m][n], 0, 0, 0);                         \
    }

    STAGE(0, 0);
    __syncthreads();
    int nt = K >> 5, cur = 0;
    for (int t = 0; t < nt - 1; ++t) {
        STAGE(cur ^ 1, (t + 1) * 32);
        COMPUTE(cur);
        __syncthreads();
        cur ^= 1;
    }
    COMPUTE(cur);
#undef STAGE
#undef COMPUTE

    // C-write
#pragma unroll
    for (int m = 0; m < 4; ++m) {
        int rbase = row0 + wr * 64 + m * 16 + lg * 4;
#pragma unroll
        for (int n = 0; n < 4; ++n) {
            int c = col0 + wc * 64 + n * 16 + lr;
            float bv = bias ? bias[c] : 0.f;
#pragma unroll
            for (int r = 0; r < 4; ++r) {
                float v = acc[m][n][r] + bv;
                if (relu_act) v = fmaxf(v, 0.f);
                Cb[(size_t)(rbase + r) * ldc + c] = f2bf(v);
            }
        }
    }

    // fused attvec + colsum epilogue
    if (av) {
        const int h = (col0 + wc * 64) >> 8;   // head uniform per wave quadrant
        float aes[4], aed[4];
#pragma unroll
        for (int n = 0; n < 4; ++n) {
            int cc = (col0 + wc * 64 + n * 16 + lr) & 255;
            aes[n] = av[h * 2 * DH + cc];
            aed[n] = av[h * 2 * DH + DH + cc];
        }
#pragma unroll
        for (int m = 0; m < 4; ++m) {
#pragma unroll
            for (int r = 0; r < 4; ++r) {
                float se = 0.f, sd = 0.f;
#pragma unroll
                for (int n = 0; n < 4; ++n) {
                    se = fmaf(aes[n], acc[m][n][r], se);
                    sd = fmaf(aed[n], acc[m][n][r], sd);
                }
                se += __shfl_xor(se, 1);  sd += __shfl_xor(sd, 1);
                se += __shfl_xor(se, 2);  sd += __shfl_xor(sd, 2);
                se += __shfl_xor(se, 4);  sd += __shfl_xor(sd, 4);
                se += __shfl_xor(se, 8);  sd += __shfl_xor(sd, 8);
                if (lr == 0) {
                    int row = row0 + wr * 64 + m * 16 + lg * 4 + r;
                    atomicAdd(&es4[row * 4 + h], se);
                    atomicAdd(&ed4[row * 4 + h], sd);
                }
            }
        }
#pragma unroll
        for (int n = 0; n < 4; ++n) {
            float s = 0.f;
#pragma unroll
            for (int m = 0; m < 4; ++m)
#pragma unroll
                for (int r = 0; r < 4; ++r)
                    s += acc[m][n][r];
            s += __shfl_xor(s, 16);
            s += __shfl_xor(s, 32);
            if (lg == 0) atomicAdd(&csum[col0 + wc * 64 + n * 16 + lr], s);
        }
    }
}

// ------------------------------------------------------------------
// CSR + CSC build
// ------------------------------------------------------------------
__global__ void count_kernel(const int* __restrict__ src, const int* __restrict__ dst,
                             int* __restrict__ counts, int* __restrict__ counts2)
{
    int e = blockIdx.x * 256 + threadIdx.x;
    atomicAdd(&counts[src[e]], 1);
    atomicAdd(&counts2[dst[e]], 1);
}

// dual scan: counts -> rowptr/cursor, counts2 -> cscptr/ccursor
__global__ void scan2_kernel(const int* __restrict__ countsA, const int* __restrict__ countsB,
                             int* __restrict__ rowptr, int* __restrict__ cursor,
                             int* __restrict__ cscptr, int* __restrict__ ccursor)
{
    __shared__ int lsumA[1024];
    __shared__ int lsumB[1024];
    int t = threadIdx.x;
    int base = t * 4;
    int a0 = countsA[base], a1 = countsA[base + 1], a2 = countsA[base + 2], a3 = countsA[base + 3];
    int b0 = countsB[base], b1 = countsB[base + 1], b2 = countsB[base + 2], b3 = countsB[base + 3];
    int sA = a0 + a1 + a2 + a3;
    int sB = b0 + b1 + b2 + b3;
    lsumA[t] = sA; lsumB[t] = sB;
    __syncthreads();
    for (int off = 1; off < 1024; off <<= 1) {
        int vA = (t >= off) ? lsumA[t - off] : 0;
        int vB = (t >= off) ? lsumB[t - off] : 0;
        __syncthreads();
        lsumA[t] += vA; lsumB[t] += vB;
        __syncthreads();
    }
    int eA = lsumA[t] - sA;
    rowptr[base] = eA;               cursor[base] = eA;
    rowptr[base + 1] = eA + a0;      cursor[base + 1] = eA + a0;
    rowptr[base + 2] = eA + a0 + a1; cursor[base + 2] = eA + a0 + a1;
    rowptr[base + 3] = eA + a0 + a1 + a2; cursor[base + 3] = eA + a0 + a1 + a2;
    int eB = lsumB[t] - sB;
    cscptr[base] = eB;               ccursor[base] = eB;
    cscptr[base + 1] = eB + b0;      ccursor[base + 1] = eB + b0;
    cscptr[base + 2] = eB + b0 + b1; ccursor[base + 2] = eB + b0 + b1;
    cscptr[base + 3] = eB + b0 + b1 + b2; ccursor[base + 3] = eB + b0 + b1 + b2;
    if (t == 1023) { rowptr[NN] = lsumA[1023]; cscptr[NN] = lsumB[1023]; }
}

// fill CSR (cdst) and CSC (cscpos = CSR position of each incoming edge)
__global__ void fill_kernel(const int* __restrict__ src, const int* __restrict__ dst,
                            int* __restrict__ cursor, int* __restrict__ ccursor,
                            int* __restrict__ cdst, int* __restrict__ cscpos)
{
    int e = blockIdx.x * 256 + threadIdx.x;
    int s = src[e], d = dst[e];
    int pos = atomicAdd(&cursor[s], 1);
    cdst[pos] = d;
    int cp = atomicAdd(&ccursor[d], 1);
    cscpos[cp] = pos;
}

// ------------------------------------------------------------------
// Fused edge-weights + denominator + aggregation; per-edge importance
// contributions written as PLAIN stores wi[csrpos] (no atomics).
// ------------------------------------------------------------------
__global__ __launch_bounds__(256)
void agg_kernel(const unsigned short* __restrict__ Whb,
                const f32x4* __restrict__ es4, const f32x4* __restrict__ ed4,
                const float* __restrict__ csum,
                const int* __restrict__ rowptr, const int* __restrict__ cdst,
                float* __restrict__ wi, float* __restrict__ Ctot,
                unsigned short* __restrict__ hb_out)
{
    __shared__ float red[4 * DCAT];      // 16 KB
    __shared__ f32x4 wlds[MAXDEG];       // 4 KB
    __shared__ int   dlds[MAXDEG];       // 1 KB
    __shared__ f32x4 swred[4];
    const int n = blockIdx.x;
    const int tid = threadIdx.x;
    const int w = tid >> 6, lane = tid & 63;
    const int beg = rowptr[n], end = rowptr[n + 1];
    const int deg = end - beg;
    const f32x4 esv = es4[n];

    // ---- Phase A: per-edge weights (each thread owns distinct edges) ----
    f32x4 sw = (f32x4){0.f, 0.f, 0.f, 0.f};
    for (int i = tid; i < deg; i += 256) {
        int d = cdst[beg + i];
        f32x4 ev = ed4[d];
        f32x4 wv;
#pragma unroll
        for (int h = 0; h < 4; ++h) {
            float v = esv[h] + ev[h];
            v = v > 0.f ? v : ALPHA_LR * v;
            wv[h] = expm1f(v);
            sw[h] += wv[h];
        }
        if (i < MAXDEG) { wlds[i] = wv; dlds[i] = d; }
    }
#pragma unroll
    for (int off = 32; off; off >>= 1) {
#pragma unroll
        for (int h = 0; h < 4; ++h) sw[h] += __shfl_down(sw[h], off);
    }
    if (lane == 0) swred[w] = sw;
    __syncthreads();

    f32x4 invdv;
#pragma unroll
    for (int h = 0; h < 4; ++h)
        invdv[h] = 1.f / ((float)NN + swred[0][h] + swred[1][h] + swred[2][h] + swred[3][h]);
    if (tid == 0)
        atomicAdd(Ctot, invdv[0] + invdv[1] + invdv[2] + invdv[3]);

    // importance contributions: plain coalesced stores, no atomics
    for (int i = tid; i < deg; i += 256) {
        f32x4 wv;
        if (i < MAXDEG) { wv = wlds[i]; }
        else {
            int d = cdst[beg + i];
            f32x4 ev = ed4[d];
#pragma unroll
            for (int h = 0; h < 4; ++h) {
                float v = esv[h] + ev[h];
                v = v > 0.f ? v : ALPHA_LR * v;
                wv[h] = expm1f(v);
            }
        }
        wi[beg + i] = fmaf(wv[0], invdv[0], fmaf(wv[1], invdv[1],
                      fmaf(wv[2], invdv[2], wv[3] * invdv[3])));
    }

    // ---- Phase B: weighted gather (4 waves split edges, 2-edge unroll) ----
    float acc[4][4] = {};
    const unsigned short* basep = Whb + lane * 4;

#define GATHER_EDGE(i)                                                          \
    {                                                                           \
        f32x4 wv; int d;                                                        \
        if ((i) < MAXDEG) { wv = wlds[(i)]; d = dlds[(i)]; }                    \
        else {                                                                  \
            d = cdst[beg + (i)];                                                \
            f32x4 ev = ed4[d];                                                  \
            _Pragma("unroll")                                                   \
            for (int h = 0; h < 4; ++h) {                                       \
                float v = esv[h] + ev[h];                                       \
                v = v > 0.f ? v : ALPHA_LR * v;                                 \
                wv[h] = expm1f(v);                                              \
            }                                                                   \
        }                                                                       \
        const unsigned short* row = basep + (size_t)d * DCAT;                   \
        s16x4 v0 = *(const s16x4*)(row);                                        \
        s16x4 v1 = *(const s16x4*)(row + DH);                                   \
        s16x4 v2 = *(const s16x4*)(row + 2 * DH);                               \
        s16x4 v3 = *(const s16x4*)(row + 3 * DH);                               \
        _Pragma("unroll")                                                       \
        for (int j = 0; j < 4; ++j) {                                           \
            acc[0][j] = fmaf(wv[0], bf2f((unsigned short)v0[j]), acc[0][j]);    \
            acc[1][j] = fmaf(wv[1], bf2f((unsigned short)v1[j]), acc[1][j]);    \
            acc[2][j] = fmaf(wv[2], bf2f((unsigned short)v2[j]), acc[2][j]);    \
            acc[3][j] = fmaf(wv[3], bf2f((unsigned short)v3[j]), acc[3][j]);    \
        }                                                                       \
    }

    {
        int i = w;
        for (; i + 4 < deg; i += 8) { GATHER_EDGE(i); GATHER_EDGE(i + 4); }
        if (i < deg) GATHER_EDGE(i);
    }
#undef GATHER_EDGE

#pragma unroll
    for (int h = 0; h < 4; ++h)
        *(f32x4*)(&red[w * DCAT + h * DH + lane * 4]) =
            (f32x4){acc[h][0], acc[h][1], acc[h][2], acc[h][3]};
    __syncthreads();

    // finish: h'[n][i] for i = 4t..4t+3 (i = h*256+o)
    f32x4 s0 = *(const f32x4*)(&red[tid * 4]);
    f32x4 s1 = *(const f32x4*)(&red[DCAT + tid * 4]);
    f32x4 s2 = *(const f32x4*)(&red[2 * DCAT + tid * 4]);
    f32x4 s3 = *(const f32x4*)(&red[3 * DCAT + tid * 4]);
    const float iv = invdv[tid >> 6];
    f32x4 cs = *(const f32x4*)(&csum[tid * 4]);
    s16x4 ob;
#pragma unroll
    for (int j = 0; j < 4; ++j) {
        float v = (cs[j] + s0[j] + s1[j] + s2[j] + s3[j]) * iv;
        v = v > 0.f ? v : expm1f(v);
        ob[j] = (short)f2bf(v);
    }
    *(s16x4*)(&hb_out[(size_t)n * DCAT + tid * 4]) = ob;
}

// ------------------------------------------------------------------
// importance gather over incoming edges (CSC), fused with natt output.
// 8 lanes per dst node; atomic-free.
// ------------------------------------------------------------------
__global__ void impgather_kernel(const int* __restrict__ cscptr, const int* __restrict__ cscpos,
                                 const float* __restrict__ wi0, const float* __restrict__ wi1,
                                 const float* __restrict__ wi2, const float* __restrict__ Ctot,
                                 float* __restrict__ out)
{
    int gid = blockIdx.x * 256 + threadIdx.x;
    int m = gid >> 3;            // dst node
    int l = gid & 7;
    int beg = cscptr[m], end = cscptr[m + 1];
    float s = 0.f;
    for (int j = beg + l; j < end; j += 8) {
        int p = cscpos[j];
        s += wi0[p] + wi1[p] + wi2[p];
    }
    s += __shfl_down(s, 4, 8);
    s += __shfl_down(s, 2, 8);
    s += __shfl_down(s, 1, 8);
    if (l == 0) out[7 + m] = (s + Ctot[0]) * (1.0f / 12.0f);
}

// ------------------------------------------------------------------
// Pooling + classifier (bf16 h3)
// ------------------------------------------------------------------
__global__ void pool_score_kernel(const unsigned short* __restrict__ h3, const float* __restrict__ pw,
                                  const float* __restrict__ pb, float* __restrict__ ps)
{
    int wave = threadIdx.x >> 6, lane = threadIdx.x & 63;
    int n = blockIdx.x * 4 + wave;
    const unsigned short* row = h3 + (size_t)n * DCAT;
    float s = 0.f;
#pragma unroll
    for (int i = 0; i < 4; ++i) {
        int o = (i * 64 + lane) * 4;
        s16x4 v = *(const s16x4*)(row + o);
        f32x4 a = *(const f32x4*)(pw + o);
#pragma unroll
        for (int j = 0; j < 4; ++j) s = fmaf(a[j], bf2f((unsigned short)v[j]), s);
    }
#pragma unroll
    for (int off = 32; off; off >>= 1) s += __shfl_down(s, off);
    if (lane == 0) ps[n] = s + pb[0];
}

__global__ void softmax_n_kernel(const float* __restrict__ s, float* __restrict__ aw)
{
    __shared__ float red[16];
    __shared__ float MM, SS;
    int t = threadIdx.x;
    float m = -1e30f;
    for (int i = t; i < NN; i += 1024) m = fmaxf(m, s[i]);
#pragma unroll
    for (int off = 32; off; off >>= 1) m = fmaxf(m, __shfl_down(m, off));
    if ((t & 63) == 0) red[t >> 6] = m;
    __syncthreads();
    if (t == 0) {
        float v = red[0];
        for (int i = 1; i < 16; ++i) v = fmaxf(v, red[i]);
        MM = v;
    }
    __syncthreads();
    float sum = 0.f;
    for (int i = t; i < NN; i += 1024) sum += expf(s[i] - MM);
#pragma unroll
    for (int off = 32; off; off >>= 1) sum += __shfl_down(sum, off);
    __syncthreads();
    if ((t & 63) == 0) red[t >> 6] = sum;
    __syncthreads();
    if (t == 0) {
        float v = 0.f;
        for (int i = 0; i < 16; ++i) v += red[i];
        SS = v;
    }
    __syncthreads();
    for (int i = t; i < NN; i += 1024) aw[i] = expf(s[i] - MM) / SS;
}

__global__ void emb_kernel(const unsigned short* __restrict__ h3, const float* __restrict__ aw,
                           float* __restrict__ emb)
{
    int o = blockIdx.x * 256 + threadIdx.x;
    int n0 = blockIdx.y * 256;
    float s = 0.f;
    for (int n = n0; n < n0 + 256; ++n)
        s = fmaf(aw[n], bf2f(h3[(size_t)n * DCAT + o]), s);
    atomicAdd(&emb[o], s);
}

// split-K matvec: zbuf[t] += sum_{j in block-chunk} emb[j]*c1w[j][t]
__global__ void c1_kernel(const float* __restrict__ emb, const float* __restrict__ c1w,
                          float* __restrict__ zbuf)
{
    int t = threadIdx.x;
    int r0 = blockIdx.x * 32;
    float s = 0.f;
#pragma unroll
    for (int j = 0; j < 32; ++j)
        s = fmaf(emb[r0 + j], c1w[(size_t)(r0 + j) * DH + t], s);
    atomicAdd(&zbuf[t], s);
}

__global__ void c2_kernel(const float* __restrict__ zbuf, const float* __restrict__ c1b,
                          const float* __restrict__ c2w, const float* __restrict__ c2b,
                          float* __restrict__ out)
{
    __shared__ float z[DH];
    __shared__ float lgs[8];
    int t = threadIdx.x;
    z[t] = fmaxf(zbuf[t] + c1b[t], 0.f);
    __syncthreads();
    int g = t >> 5, k = t & 31;
    if (g < 7) {
        float s = 0.f;
#pragma unroll
        for (int j = 0; j < 8; ++j)
            s = fmaf(z[k + 32 * j], c2w[(k + 32 * j) * 7 + g], s);
#pragma unroll
        for (int off = 16; off; off >>= 1) s += __shfl_down(s, off, 32);
        if (k == 0) lgs[g] = s + c2b[g];
    }
    __syncthreads();
    if (t == 0) {
        float m = lgs[0];
        for (int i = 1; i < 7; ++i) m = fmaxf(m, lgs[i]);
        float sm = 0.f, ex[7];
        for (int i = 0; i < 7; ++i) { ex[i] = expf(lgs[i] - m); sm += ex[i]; }
        for (int i = 0; i < 7; ++i) out[i] = ex[i] / sm;
    }
}

// ------------------------------------------------------------------
extern "C" void kernel_launch(void* const* d_in, const int* in_sizes, int n_in,
                              void* d_out, int out_size, void* d_ws, size_t ws_size,
                              hipStream_t stream)
{
    const float* x   = (const float*)d_in[0];
    const int*   ei  = (const int*)d_in[1];
    const float* Wp  = (const float*)d_in[2];
    const float* bp  = (const float*)d_in[3];
    const float* W[3]  = {(const float*)d_in[4], (const float*)d_in[6], (const float*)d_in[8]};
    const float* av[3] = {(const float*)d_in[5], (const float*)d_in[7], (const float*)d_in[9]};
    const float* pw  = (const float*)d_in[10];
    const float* pb  = (const float*)d_in[11];
    const float* c1w = (const float*)d_in[12];
    const float* c1b = (const float*)d_in[13];
    const float* c2w = (const float*)d_in[14];
    const float* c2b = (const float*)d_in[15];
    float* out = (float*)d_out;
    (void)in_sizes; (void)n_in; (void)out_size; (void)ws_size;

    char* base = (char*)d_ws;
    size_t off = 0;
    auto alloc = [&](size_t bytes) -> void* {
        void* p = base + off;
        off = (off + bytes + 255) & ~(size_t)255;
        return p;
    };
    // ---- zero region (single memset) ----
    size_t zero_begin = off;
    float* es4_3 = (float*)alloc((size_t)3 * NN * 16);   // [layer][n][4]
    float* ed4_3 = (float*)alloc((size_t)3 * NN * 16);
    float* csum3 = (float*)alloc((size_t)3 * DCAT * 4);
    float* Ctot  = (float*)alloc(256);
    int*   counts  = (int*)alloc(NN * 4);
    int*   counts2 = (int*)alloc(NN * 4);
    float* emb   = (float*)alloc(DCAT * 4);
    float* zbuf  = (float*)alloc(DH * 4);
    size_t zero_bytes = off - zero_begin;
    // ---- rest ----
    unsigned short* xb   = (unsigned short*)alloc((size_t)NN * DIN * 2);
    unsigned short* BTp  = (unsigned short*)alloc((size_t)DH * DIN * 2);
    unsigned short* BT0  = (unsigned short*)alloc((size_t)DCAT * DH * 2);
    unsigned short* BT1  = (unsigned short*)alloc((size_t)DCAT * DCAT * 2);
    unsigned short* BT2  = (unsigned short*)alloc((size_t)DCAT * DCAT * 2);
    unsigned short* Whb  = (unsigned short*)alloc((size_t)NN * DCAT * 2);
    unsigned short* hb0  = (unsigned short*)alloc((size_t)NN * DCAT * 2);
    unsigned short* hb1  = (unsigned short*)alloc((size_t)NN * DCAT * 2);
    int*   rowptr  = (int*)alloc((NN + 1) * 4);
    int*   cursor  = (int*)alloc(NN * 4);
    int*   cscptr  = (int*)alloc((NN + 1) * 4);
    int*   ccursor = (int*)alloc(NN * 4);
    int*   cdst    = (int*)alloc((size_t)EE * 4);
    int*   cscpos  = (int*)alloc((size_t)EE * 4);
    float* wi3     = (float*)alloc((size_t)3 * EE * 4);
    float* ps    = (float*)alloc(NN * 4);
    float* paw   = (float*)alloc(NN * 4);

    const int* srcp = ei;
    const int* dstp = ei + EE;

    hipMemsetAsync(base + zero_begin, 0, zero_bytes, stream);

    // CSR + CSC build
    count_kernel<<<EE / 256, 256, 0, stream>>>(srcp, dstp, counts, counts2);
    scan2_kernel<<<1, 1024, 0, stream>>>(counts, counts2, rowptr, cursor, cscptr, ccursor);
    fill_kernel<<<EE / 256, 256, 0, stream>>>(srcp, dstp, cursor, ccursor, cdst, cscpos);

    // casts / repacks
    cast_kernel<<<(NN * DIN / 4 + 255) / 256, 256, 0, stream>>>(x, xb, NN * DIN / 4);
    transpose_cast_kernel<<<dim3(DIN / 32, 8, 1), 256, 0, stream>>>(Wp, BTp, DIN);
    transpose_cast_kernel<<<dim3(DH / 32, 8, HH), 256, 0, stream>>>(W[0], BT0, DH);
    transpose_cast2_kernel<<<dim3(DCAT / 32, 8, 8), 256, 0, stream>>>(W[1], W[2], BT1, BT2);

    // projection: hb0[N][256] = relu(x @ Wp + bp)
    mfma_gemm_kernel<<<dim3(NN / 128, DH / 128), 256, 0, stream>>>(
        xb, BTp, DIN, hb0, DH, bp, 1, nullptr, nullptr, nullptr, nullptr);

    unsigned short* cur = hb0;
    unsigned short* nxt = hb1;
    const unsigned short* BTl[3] = {BT0, BT1, BT2};
    for (int layer = 0; layer < 3; ++layer) {
        int K = (layer == 0) ? DH : DCAT;
        float* es = es4_3 + (size_t)layer * NN * 4;
        float* ed = ed4_3 + (size_t)layer * NN * 4;
        float* csum = csum3 + (size_t)layer * DCAT;
        float* wi = wi3 + (size_t)layer * EE;
        mfma_gemm_kernel<<<dim3(NN / 128, DCAT / 128), 256, 0, stream>>>(
            cur, BTl[layer], K, Whb, DCAT, nullptr, 0, av[layer], es, ed, csum);
        agg_kernel<<<NN, 256, 0, stream>>>(Whb, (const f32x4*)es, (const f32x4*)ed,
                                           csum, rowptr, cdst, wi, Ctot, nxt);
        unsigned short* t = cur; cur = nxt; nxt = t;
    }

    // pooling + classifier on bf16 h3 (cur)
    pool_score_kernel<<<NN / 4, 256, 0, stream>>>(cur, pw, pb, ps);
    softmax_n_kernel<<<1, 1024, 0, stream>>>(ps, paw);
    emb_kernel<<<dim3(DCAT / 256, NN / 256), 256, 0, stream>>>(cur, paw, emb);
    c1_kernel<<<32, 256, 0, stream>>>(emb, c1w, zbuf);
    c2_kernel<<<1, 256, 0, stream>>>(zbuf, c1b, c2w, c2b, out);

    // importance (atomic-free CSC gather) + node_attention output
    impgather_kernel<<<NN * 8 / 256, 256, 0, stream>>>(cscptr, cscpos,
        wi3, wi3 + EE, wi3 + 2 * EE, Ctot, out);
}